// Round 14
// baseline (123.088 us; speedup 1.0000x reference)
//
#include <hip/hip_runtime.h>
#include <math.h>

#define BB 4
#define NN 4096
#define DD 128
#define HS 16            // n slices per batch (256 n each)
#define NT2 8            // 32-n tiles per slice
#define QB 32            // m block-groups per batch (128 m each; 4 waves x 32)

typedef __attribute__((ext_vector_type(8))) short bf16x8;
typedef __attribute__((ext_vector_type(4))) float f32x4;
typedef __attribute__((ext_vector_type(4))) unsigned short u16x4;

__device__ __forceinline__ void mfma_16x16x32_bf16(f32x4& d, bf16x8 a, bf16x8 b) {
  asm volatile("v_mfma_f32_16x16x32_bf16 %0, %1, %2, %0" : "+v"(d) : "v"(a), "v"(b));
}

__device__ __forceinline__ float vexp2(float x) {  // raw v_exp_f32 = 2^x
  float r; asm("v_exp_f32 %0, %1" : "=v"(r) : "v"(x)); return r;
}

__device__ __forceinline__ unsigned short f2b(float x) {  // RNE f32->bf16
  union { float f; unsigned u; } v; v.f = x;
  unsigned r = v.u + 0x7fffu + ((v.u >> 16) & 1u);
  return (unsigned short)(r >> 16);
}

// ---- kernel 1: cast to bf16 (ft pre-scaled by 0.1*log2e) + fs inv-norms ----
__global__ __launch_bounds__(256) void k_prep(const float* __restrict__ fs,
                                              const float* __restrict__ ft,
                                              unsigned short* __restrict__ fsb,
                                              unsigned short* __restrict__ ftb,
                                              float* __restrict__ inv_norm) {
  int i = blockIdx.x * 256 + threadIdx.x;    // float4 index
  float4 a = ((const float4*)fs)[i];
  float4 c = ((const float4*)ft)[i];
  u16x4 oa; oa[0] = f2b(a.x); oa[1] = f2b(a.y); oa[2] = f2b(a.z); oa[3] = f2b(a.w);
  ((u16x4*)fsb)[i] = oa;
  const float C = 0.14426950408889634f;      // 0.1*log2(e): 2^acc == exp(dot/10)
  u16x4 oc; oc[0] = f2b(c.x * C); oc[1] = f2b(c.y * C);
  oc[2] = f2b(c.z * C); oc[3] = f2b(c.w * C);
  ((u16x4*)ftb)[i] = oc;
  float s = a.x * a.x + a.y * a.y + a.z * a.z + a.w * a.w;
#pragma unroll
  for (int off = 1; off <= 16; off <<= 1) s += __shfl_xor(s, off);
  if ((threadIdx.x & 31) == 0) inv_norm[i >> 5] = 1.0f / sqrtf(s);
}

// ---- kernel 2: barrier-free reg-staged GEMM C[m][n], 32 m-rows per wave ----
// r13's skeleton (no in-loop barriers, B frags global->reg with explicit
// dbuf) re-dimensioned for residency: r13 had 512 blocks = 2/CU = 1.5
// waves/SIMD -> latency-bound at VALUBusy 31%. Now: 2048 blocks, VGPR ~105
// (af[4][2]=32), launch_bounds(256,4) -> 4 blocks/CU resident, 4 waves/SIMD,
// barrier-free so waves self-desynchronize and co-fill VALU/trans/MFMA.
__global__ __launch_bounds__(256, 4) void k_main(const unsigned short* __restrict__ fsb,
                                                 const unsigned short* __restrict__ ftb,
                                                 const float* __restrict__ inv_norm,
                                                 float* __restrict__ psum,
                                                 float2* __restrict__ pmax) {
  __shared__ float psb[4 * 256];     // per-wave exp-sum partials
  __shared__ float sInv[256];        // inv_norm slice

  const int t = threadIdx.x;
  const int w = t >> 6, lane = t & 63;
  const int l15 = lane & 15, g = lane >> 4;
  const int bid = blockIdx.x;
  const int qb = bid & 31, h = (bid >> 5) & 15, b = bid >> 9;
  const int m0 = qb * 128 + w * 32;

  // A fragments: ft rows m0..m0+31 (pre-scaled), loaded once: 32 VGPR
  const unsigned short* Ab = ftb + ((size_t)b * NN + m0) * DD;
  bf16x8 af[4][2];
#pragma unroll
  for (int kk = 0; kk < 4; kk++)
#pragma unroll
    for (int mf = 0; mf < 2; mf++)
      af[kk][mf] = *(const bf16x8*)(Ab + (mf * 16 + l15) * DD + kk * 32 + g * 8);

  // inv_norm slice -> LDS (1 float/thread)
  sInv[t] = inv_norm[(size_t)b * NN + h * 256 + t];
  __syncthreads();

  // per-lane fragment base: row l15, K-chunk g (byte offsets within 8KB tile)
  const char* gBlane = (const char*)(fsb + ((size_t)b * NN + h * 256) * DD)
                       + l15 * 256 + g * 16;

  float bkey[2][4];
#pragma unroll
  for (int mf = 0; mf < 2; mf++)
#pragma unroll
    for (int j = 0; j < 4; j++) bkey[mf][j] = 0.0f;

  bf16x8 bfA[8], bfB[8];

  // tile load: 8 dwordx4 from one base + immediate offsets (fj*4096 + kk*64)
#define LOAD_TILE(dst, it)                                                   \
  {                                                                          \
    const char* p = gBlane + (it) * 8192;                                    \
    _Pragma("unroll")                                                        \
    for (int kk = 0; kk < 4; kk++) {                                         \
      dst[kk * 2 + 0] = *(const bf16x8*)(p + kk * 64);                       \
      dst[kk * 2 + 1] = *(const bf16x8*)(p + 4096 + kk * 64);                \
    }                                                                        \
  }

#define COMPUTE_TILE(bf, it)                                                 \
  {                                                                          \
    f32x4 acc[2][2] = {};                                                    \
    _Pragma("unroll")                                                        \
    for (int kk = 0; kk < 4; kk++)                                           \
      _Pragma("unroll")                                                      \
      for (int mf = 0; mf < 2; mf++) {                                       \
        mfma_16x16x32_bf16(acc[mf][0], af[kk][mf], bf[kk * 2 + 0]);          \
        mfma_16x16x32_bf16(acc[mf][1], af[kk][mf], bf[kk * 2 + 1]);          \
      }                                                                      \
    _Pragma("unroll")                                                        \
    for (int fj = 0; fj < 2; fj++) {                                         \
      float e0 = vexp2(acc[0][fj][0]), e1 = vexp2(acc[0][fj][1]);            \
      float e2 = vexp2(acc[0][fj][2]), e3 = vexp2(acc[0][fj][3]);            \
      float e4 = vexp2(acc[1][fj][0]), e5 = vexp2(acc[1][fj][1]);            \
      float e6 = vexp2(acc[1][fj][2]), e7 = vexp2(acc[1][fj][3]);            \
      float s = ((e0 + e1) + (e2 + e3)) + ((e4 + e5) + (e6 + e7));           \
      s += __shfl_xor(s, 16);                                                \
      s += __shfl_xor(s, 32);                                                \
      if (g == 0) psb[w * 256 + (it) * 32 + fj * 16 + l15] = s;              \
      float svn = sInv[(it) * 32 + fj * 16 + l15];                           \
      const unsigned code = (unsigned)((7 - (it)) << 1) | (unsigned)(1 - fj);\
      _Pragma("unroll")                                                      \
      for (int mf = 0; mf < 2; mf++)                                         \
        _Pragma("unroll")                                                    \
        for (int j = 0; j < 4; j++) {                                        \
          float v = fmaf(acc[mf][fj][j], svn, 4.0f);                         \
          unsigned kb = (__float_as_uint(v) & 0xFFFFFFF0u) | code;           \
          bkey[mf][j] = fmaxf(bkey[mf][j], __uint_as_float(kb));             \
        }                                                                    \
    }                                                                        \
  }

  LOAD_TILE(bfA, 0)
#pragma unroll 1
  for (int itp = 0; itp < NT2 / 2; ++itp) {
    const int it0 = itp * 2, it1 = itp * 2 + 1;
    LOAD_TILE(bfB, it1)
    COMPUTE_TILE(bfA, it0)
    if (itp < NT2 / 2 - 1) LOAD_TILE(bfA, it1 + 1)
    COMPUTE_TILE(bfB, it1)
  }

  // pmax finalize: exact cross-l15 argmax, once per wave (32 private m-rows)
#pragma unroll
  for (int mf = 0; mf < 2; mf++)
#pragma unroll
    for (int j = 0; j < 4; j++) {
      unsigned bits = __float_as_uint(bkey[mf][j]);
      unsigned code = bits & 15u;
      int itw = 7 - (int)(code >> 1);
      int fjw = 1 - (int)(code & 1u);
      int n = h * 256 + itw * 32 + fjw * 16 + l15;
      float vq = __uint_as_float(bits & 0xFFFFFFF0u);
#pragma unroll
      for (int off = 1; off <= 8; off <<= 1) {
        float ov = __shfl_xor(vq, off);
        int   on = __shfl_xor(n, off);
        if (ov > vq || (ov == vq && on < n)) { vq = ov; n = on; }
      }
      if (l15 == 0) {
        int m = m0 + mf * 16 + g * 4 + j;
        float2 pr; pr.x = vq; pr.y = __int_as_float(n);
        pmax[((size_t)b * NN + m) * HS + h] = pr;
      }
    }

  __syncthreads();   // psb complete block-wide (only barrier after prologue)

  // psum write-out: combine 4 waves, coalesced (layout psum[b][qb][n])
  {
    float s4 = (psb[t] + psb[256 + t]) + (psb[512 + t] + psb[768 + t]);
    psum[((size_t)(b * QB + qb)) * NN + h * 256 + t] = s4;
  }
#undef LOAD_TILE
#undef COMPUTE_TILE
}

// ---- kernel 3: per-row finish: argmax over 16 slices, sum 32 psum, pos dot -
__global__ __launch_bounds__(256) void k_post(const float* __restrict__ fs,
                                              const float* __restrict__ ft,
                                              const float* __restrict__ psum,
                                              const float2* __restrict__ pmax,
                                              float* __restrict__ blockpart) {
  __shared__ float part[4];
  int w = threadIdx.x >> 6, lane = threadIdx.x & 63;
  int row = blockIdx.x * 4 + w;          // flat b*N + p
  int b = row >> 12, pn = row & (NN - 1);
  // argmax over the 16 h-slices
  float v = -INFINITY; int i = 0x7fffffff;
  if (lane < HS) {
    float2 pm = pmax[(size_t)row * HS + lane];
    v = pm.x; i = __float_as_int(pm.y);
  }
#pragma unroll
  for (int off = 1; off <= 8; off <<= 1) {
    float ov = __shfl_xor(v, off);
    int   oi = __shfl_xor(i, off);
    if (ov > v || (ov == v && oi < i)) { v = ov; i = oi; }
  }
  int j = __shfl(i, 0);
  // sum the 32 qb-partials of all_exp
  float tot = (lane < QB) ? psum[((size_t)(b * QB + lane)) * NN + pn] : 0.0f;
#pragma unroll
  for (int off = 1; off <= 16; off <<= 1) tot += __shfl_xor(tot, off);
  // fp32 dot of fs[row] with ft[b, j]
  float2 a = ((const float2*)(fs + (size_t)row * DD))[lane];
  float2 c = ((const float2*)(ft + ((size_t)b * NN + j) * DD))[lane];
  float s = a.x * c.x + a.y * c.y;
#pragma unroll
  for (int off = 32; off > 0; off >>= 1) s += __shfl_xor(s, off);
  if (lane == 0) {
    float term = logf(tot) - s * 0.1f;
    part[w] = fminf(term, 92.103403719761827f);   // ratio clip at 1e-40
  }
  __syncthreads();
  if (threadIdx.x == 0)
    blockpart[blockIdx.x] = part[0] + part[1] + part[2] + part[3];
}

// ---- kernel 4: final deterministic reduction ------------------------------
__global__ __launch_bounds__(256) void k_final(const float* __restrict__ blockpart,
                                               float* __restrict__ out) {
  __shared__ float red[256];
  float s = 0.0f;
  for (int i = threadIdx.x; i < (BB * NN) / 4; i += 256) s += blockpart[i];
  red[threadIdx.x] = s;
  __syncthreads();
  for (int st = 128; st > 0; st >>= 1) {
    if (threadIdx.x < st) red[threadIdx.x] += red[threadIdx.x + st];
    __syncthreads();
  }
  if (threadIdx.x == 0) out[0] = red[0] * (1.0f / (BB * NN));
}

extern "C" void kernel_launch(void* const* d_in, const int* in_sizes, int n_in,
                              void* d_out, int out_size, void* d_ws, size_t ws_size,
                              hipStream_t stream) {
  const float* fs = (const float*)d_in[0];
  const float* ft = (const float*)d_in[1];
  float* out = (float*)d_out;

  const size_t NE = (size_t)BB * NN * DD;
  unsigned short* fsb = (unsigned short*)d_ws;                   // 4MB
  unsigned short* ftb = fsb + NE;                                // 4MB
  float*  inv_norm = (float*)(ftb + NE);                         // 64KB
  float*  psum     = inv_norm + (size_t)BB * NN;                 // B*32*N f32 (2MB)
  float2* pmax     = (float2*)(psum + (size_t)BB * QB * NN);     // B*N*16 f32x2 (2MB)
  float*  blockpart = (float*)(pmax + (size_t)BB * NN * HS);     // B*N/4 f32

  k_prep<<<(int)(NE / 4 / 256), 256, 0, stream>>>(fs, ft, fsb, ftb, inv_norm);
  // k_main: b(4) x h(16) x qb(32) = 2048 blocks, 8192 independent waves
  k_main<<<BB * HS * QB, 256, 0, stream>>>(fsb, ftb, inv_norm, psum, pmax);
  k_post<<<(BB * NN) / 4, 256, 0, stream>>>(fs, ft, psum, pmax, blockpart);
  k_final<<<1, 256, 0, stream>>>(blockpart, out);
}

// Round 15
// 73.852 us; speedup vs baseline: 1.6667x; 1.6667x over previous
//
#include <hip/hip_runtime.h>
#include <math.h>

#define BB 4
#define NN 4096
#define DD 128
#define HS 16            // n slices per batch (256 n each)
#define NT2 8            // 32-n tiles per slice
#define QG 16            // m quad-groups per batch (256 m each; 4 waves x 64)

typedef __attribute__((ext_vector_type(8))) short bf16x8;
typedef __attribute__((ext_vector_type(4))) float f32x4;
typedef __attribute__((ext_vector_type(4))) unsigned short u16x4;

__device__ __forceinline__ void mfma_16x16x32_bf16(f32x4& d, bf16x8 a, bf16x8 b) {
  asm volatile("v_mfma_f32_16x16x32_bf16 %0, %1, %2, %0" : "+v"(d) : "v"(a), "v"(b));
}

__device__ __forceinline__ float vexp2(float x) {  // raw v_exp_f32 = 2^x
  float r; asm("v_exp_f32 %0, %1" : "=v"(r) : "v"(x)); return r;
}

__device__ __forceinline__ unsigned short f2b(float x) {  // RNE f32->bf16
  union { float f; unsigned u; } v; v.f = x;
  unsigned r = v.u + 0x7fffu + ((v.u >> 16) & 1u);
  return (unsigned short)(r >> 16);
}

// ---- kernel 1: cast to bf16 (ft pre-scaled by 0.1*log2e) + fs inv-norms ----
__global__ __launch_bounds__(256) void k_prep(const float* __restrict__ fs,
                                              const float* __restrict__ ft,
                                              unsigned short* __restrict__ fsb,
                                              unsigned short* __restrict__ ftb,
                                              float* __restrict__ inv_norm) {
  int i = blockIdx.x * 256 + threadIdx.x;    // float4 index
  float4 a = ((const float4*)fs)[i];
  float4 c = ((const float4*)ft)[i];
  u16x4 oa; oa[0] = f2b(a.x); oa[1] = f2b(a.y); oa[2] = f2b(a.z); oa[3] = f2b(a.w);
  ((u16x4*)fsb)[i] = oa;
  const float C = 0.14426950408889634f;      // 0.1*log2(e): 2^acc == exp(dot/10)
  u16x4 oc; oc[0] = f2b(c.x * C); oc[1] = f2b(c.y * C);
  oc[2] = f2b(c.z * C); oc[3] = f2b(c.w * C);
  ((u16x4*)ftb)[i] = oc;
  float s = a.x * a.x + a.y * a.y + a.z * a.z + a.w * a.w;
#pragma unroll
  for (int off = 1; off <= 16; off <<= 1) s += __shfl_xor(s, off);
  if ((threadIdx.x & 31) == 0) inv_norm[i >> 5] = 1.0f / sqrtf(s);
}

// ---- kernel 2: barrier-free reg-staged GEMM C[m][n], 64 m-rows per wave ----
// EXACTLY round 13's body (VGPR=112, zero spill at launch_bounds(256,2)) with
// the grid doubled: n-slices halved to 256 (HS=16, NT2=8) -> 1024 blocks =
// 4 blocks/CU resident (r13's 512 blocks = 2/CU = 1.5 waves/SIMD was the
// limiter, NOT the structure). r14's (256,4) cap=128 < ~140-reg working set
// spilled 186MB -- residency must come from grid, not the register cap.
__global__ __launch_bounds__(256, 2) void k_main(const unsigned short* __restrict__ fsb,
                                                 const unsigned short* __restrict__ ftb,
                                                 const float* __restrict__ inv_norm,
                                                 float* __restrict__ psum,
                                                 float2* __restrict__ pmax) {
  __shared__ float psb[4 * 256];     // per-wave exp-sum partials
  __shared__ float sInv[256];        // inv_norm slice

  const int t = threadIdx.x;
  const int w = t >> 6, lane = t & 63;
  const int l15 = lane & 15, g = lane >> 4;
  const int bid = blockIdx.x;
  const int qg = bid & 15, h = (bid >> 4) & 15, b = bid >> 8;
  const int m0 = qg * 256 + w * 64;

  // A fragments: ft rows m0..m0+63 (pre-scaled), loaded once: 64 VGPR
  const unsigned short* Ab = ftb + ((size_t)b * NN + m0) * DD;
  bf16x8 af[4][4];
#pragma unroll
  for (int kk = 0; kk < 4; kk++)
#pragma unroll
    for (int mf = 0; mf < 4; mf++)
      af[kk][mf] = *(const bf16x8*)(Ab + (mf * 16 + l15) * DD + kk * 32 + g * 8);

  // inv_norm slice -> LDS (1 float/thread)
  sInv[t] = inv_norm[(size_t)b * NN + h * 256 + t];
  __syncthreads();

  // per-lane fragment base: row l15, K-chunk g (byte offsets within 8KB tile)
  const char* gBlane = (const char*)(fsb + ((size_t)b * NN + h * 256) * DD)
                       + l15 * 256 + g * 16;

  float bkey[4][4];
#pragma unroll
  for (int mf = 0; mf < 4; mf++)
#pragma unroll
    for (int j = 0; j < 4; j++) bkey[mf][j] = 0.0f;

  bf16x8 bfA[8], bfB[8];

  // tile load: 8 dwordx4 from one base + immediate offsets (fj*4096 + kk*64)
#define LOAD_TILE(dst, it)                                                   \
  {                                                                          \
    const char* p = gBlane + (it) * 8192;                                    \
    _Pragma("unroll")                                                        \
    for (int kk = 0; kk < 4; kk++) {                                         \
      dst[kk * 2 + 0] = *(const bf16x8*)(p + kk * 64);                       \
      dst[kk * 2 + 1] = *(const bf16x8*)(p + 4096 + kk * 64);                \
    }                                                                        \
  }

#define COMPUTE_TILE(bf, it)                                                 \
  {                                                                          \
    f32x4 acc[4][2] = {};                                                    \
    _Pragma("unroll")                                                        \
    for (int kk = 0; kk < 4; kk++)                                           \
      _Pragma("unroll")                                                      \
      for (int mf = 0; mf < 4; mf++) {                                       \
        mfma_16x16x32_bf16(acc[mf][0], af[kk][mf], bf[kk * 2 + 0]);          \
        mfma_16x16x32_bf16(acc[mf][1], af[kk][mf], bf[kk * 2 + 1]);          \
      }                                                                      \
    _Pragma("unroll")                                                        \
    for (int fj = 0; fj < 2; fj++) {                                         \
      float s = 0.0f;                                                        \
      _Pragma("unroll")                                                      \
      for (int mf = 0; mf < 4; mf++) {                                       \
        float e0 = vexp2(acc[mf][fj][0]), e1 = vexp2(acc[mf][fj][1]);        \
        float e2 = vexp2(acc[mf][fj][2]), e3 = vexp2(acc[mf][fj][3]);        \
        s += (e0 + e1) + (e2 + e3);                                          \
      }                                                                      \
      s += __shfl_xor(s, 16);                                                \
      s += __shfl_xor(s, 32);                                                \
      if (g == 0) psb[w * 256 + (it) * 32 + fj * 16 + l15] = s;              \
      float svn = sInv[(it) * 32 + fj * 16 + l15];                           \
      const unsigned code = (unsigned)((7 - (it)) << 1) | (unsigned)(1 - fj);\
      _Pragma("unroll")                                                      \
      for (int mf = 0; mf < 4; mf++)                                         \
        _Pragma("unroll")                                                    \
        for (int j = 0; j < 4; j++) {                                        \
          float v = fmaf(acc[mf][fj][j], svn, 4.0f);                         \
          unsigned kb = (__float_as_uint(v) & 0xFFFFFFF0u) | code;           \
          bkey[mf][j] = fmaxf(bkey[mf][j], __uint_as_float(kb));             \
        }                                                                    \
    }                                                                        \
  }

  LOAD_TILE(bfA, 0)
#pragma unroll 1
  for (int itp = 0; itp < NT2 / 2; ++itp) {
    const int it0 = itp * 2, it1 = itp * 2 + 1;
    LOAD_TILE(bfB, it1)
    COMPUTE_TILE(bfA, it0)
    if (itp < NT2 / 2 - 1) LOAD_TILE(bfA, it1 + 1)
    COMPUTE_TILE(bfB, it1)
  }

  // pmax finalize: exact cross-l15 argmax, once per wave (64 private m-rows)
#pragma unroll
  for (int mf = 0; mf < 4; mf++)
#pragma unroll
    for (int j = 0; j < 4; j++) {
      unsigned bits = __float_as_uint(bkey[mf][j]);
      unsigned code = bits & 15u;
      int itw = 7 - (int)(code >> 1);
      int fjw = 1 - (int)(code & 1u);
      int n = h * 256 + itw * 32 + fjw * 16 + l15;
      float vq = __uint_as_float(bits & 0xFFFFFFF0u);
#pragma unroll
      for (int off = 1; off <= 8; off <<= 1) {
        float ov = __shfl_xor(vq, off);
        int   on = __shfl_xor(n, off);
        if (ov > vq || (ov == vq && on < n)) { vq = ov; n = on; }
      }
      if (l15 == 0) {
        int m = m0 + mf * 16 + g * 4 + j;
        float2 pr; pr.x = vq; pr.y = __int_as_float(n);
        pmax[((size_t)b * NN + m) * HS + h] = pr;
      }
    }

  __syncthreads();   // psb complete block-wide (only barrier after prologue)

  // psum write-out: combine 4 waves, coalesced (layout psum[b][qg][n])
  {
    float s4 = (psb[t] + psb[256 + t]) + (psb[512 + t] + psb[768 + t]);
    psum[((size_t)(b * QG + qg)) * NN + h * 256 + t] = s4;
  }
#undef LOAD_TILE
#undef COMPUTE_TILE
}

// ---- kernel 3: per-row finish: argmax over 16 slices, sum 16 psum, pos dot -
__global__ __launch_bounds__(256) void k_post(const float* __restrict__ fs,
                                              const float* __restrict__ ft,
                                              const float* __restrict__ psum,
                                              const float2* __restrict__ pmax,
                                              float* __restrict__ blockpart) {
  __shared__ float part[4];
  int w = threadIdx.x >> 6, lane = threadIdx.x & 63;
  int row = blockIdx.x * 4 + w;          // flat b*N + p
  int b = row >> 12, pn = row & (NN - 1);
  // argmax over the 16 h-slices
  float v = -INFINITY; int i = 0x7fffffff;
  if (lane < HS) {
    float2 pm = pmax[(size_t)row * HS + lane];
    v = pm.x; i = __float_as_int(pm.y);
  }
#pragma unroll
  for (int off = 1; off <= 8; off <<= 1) {
    float ov = __shfl_xor(v, off);
    int   oi = __shfl_xor(i, off);
    if (ov > v || (ov == v && oi < i)) { v = ov; i = oi; }
  }
  int j = __shfl(i, 0);
  // sum the 16 qg-partials of all_exp
  float tot = (lane < QG) ? psum[((size_t)(b * QG + lane)) * NN + pn] : 0.0f;
#pragma unroll
  for (int off = 1; off <= 8; off <<= 1) tot += __shfl_xor(tot, off);
  // fp32 dot of fs[row] with ft[b, j]
  float2 a = ((const float2*)(fs + (size_t)row * DD))[lane];
  float2 c = ((const float2*)(ft + ((size_t)b * NN + j) * DD))[lane];
  float s = a.x * c.x + a.y * c.y;
#pragma unroll
  for (int off = 32; off > 0; off >>= 1) s += __shfl_xor(s, off);
  if (lane == 0) {
    float term = logf(tot) - s * 0.1f;
    part[w] = fminf(term, 92.103403719761827f);   // ratio clip at 1e-40
  }
  __syncthreads();
  if (threadIdx.x == 0)
    blockpart[blockIdx.x] = part[0] + part[1] + part[2] + part[3];
}

// ---- kernel 4: final deterministic reduction ------------------------------
__global__ __launch_bounds__(256) void k_final(const float* __restrict__ blockpart,
                                               float* __restrict__ out) {
  __shared__ float red[256];
  float s = 0.0f;
  for (int i = threadIdx.x; i < (BB * NN) / 4; i += 256) s += blockpart[i];
  red[threadIdx.x] = s;
  __syncthreads();
  for (int st = 128; st > 0; st >>= 1) {
    if (threadIdx.x < st) red[threadIdx.x] += red[threadIdx.x + st];
    __syncthreads();
  }
  if (threadIdx.x == 0) out[0] = red[0] * (1.0f / (BB * NN));
}

extern "C" void kernel_launch(void* const* d_in, const int* in_sizes, int n_in,
                              void* d_out, int out_size, void* d_ws, size_t ws_size,
                              hipStream_t stream) {
  const float* fs = (const float*)d_in[0];
  const float* ft = (const float*)d_in[1];
  float* out = (float*)d_out;

  const size_t NE = (size_t)BB * NN * DD;
  unsigned short* fsb = (unsigned short*)d_ws;                   // 4MB
  unsigned short* ftb = fsb + NE;                                // 4MB
  float*  inv_norm = (float*)(ftb + NE);                         // 64KB
  float*  psum     = inv_norm + (size_t)BB * NN;                 // B*16*N f32 (1MB)
  float2* pmax     = (float2*)(psum + (size_t)BB * QG * NN);     // B*N*16 f32x2 (2MB)
  float*  blockpart = (float*)(pmax + (size_t)BB * NN * HS);     // B*N/4 f32

  k_prep<<<(int)(NE / 4 / 256), 256, 0, stream>>>(fs, ft, fsb, ftb, inv_norm);
  // k_main: b(4) x h(16) x qg(16) = 1024 blocks, 4096 independent waves
  k_main<<<BB * HS * QG, 256, 0, stream>>>(fsb, ftb, inv_norm, psum, pmax);
  k_post<<<(BB * NN) / 4, 256, 0, stream>>>(fs, ft, psum, pmax, blockpart);
  k_final<<<1, 256, 0, stream>>>(blockpart, out);
}

// Round 16
// 56.927 us; speedup vs baseline: 2.1622x; 1.2973x over previous
//
#include <hip/hip_runtime.h>
#include <math.h>

#define BB 4
#define NN 4096
#define DD 128
#define HS 16            // n slices per batch (256 n each)
#define NIT 8            // 32-n tiles per slice
#define QG 32            // m quad-groups per batch (128 m each; 4 waves x 32)

typedef __attribute__((ext_vector_type(8))) short bf16x8;
typedef __attribute__((ext_vector_type(4))) float f32x4;
typedef __attribute__((ext_vector_type(4))) unsigned short u16x4;

__device__ __forceinline__ void mfma_16x16x32_bf16(f32x4& d, bf16x8 a, bf16x8 b) {
  asm volatile("v_mfma_f32_16x16x32_bf16 %0, %1, %2, %0" : "+v"(d) : "v"(a), "v"(b));
}

__device__ __forceinline__ void gload16(const void* g, void* lds) {
  __builtin_amdgcn_global_load_lds(
      (const __attribute__((address_space(1))) void*)g,
      (__attribute__((address_space(3))) void*)lds, 16, 0, 0);
}

__device__ __forceinline__ float vexp2(float x) {  // raw v_exp_f32 = 2^x
  float r; asm("v_exp_f32 %0, %1" : "=v"(r) : "v"(x)); return r;
}

__device__ __forceinline__ unsigned short f2b(float x) {  // RNE f32->bf16
  union { float f; unsigned u; } v; v.f = x;
  unsigned r = v.u + 0x7fffu + ((v.u >> 16) & 1u);
  return (unsigned short)(r >> 16);
}

// ---- kernel 1: cast to bf16 (ft pre-scaled by 0.1*log2e) + fs inv-norms ----
__global__ __launch_bounds__(256) void k_prep(const float* __restrict__ fs,
                                              const float* __restrict__ ft,
                                              unsigned short* __restrict__ fsb,
                                              unsigned short* __restrict__ ftb,
                                              float* __restrict__ inv_norm) {
  int i = blockIdx.x * 256 + threadIdx.x;    // float4 index
  float4 a = ((const float4*)fs)[i];
  float4 c = ((const float4*)ft)[i];
  u16x4 oa; oa[0] = f2b(a.x); oa[1] = f2b(a.y); oa[2] = f2b(a.z); oa[3] = f2b(a.w);
  ((u16x4*)fsb)[i] = oa;
  const float C = 0.14426950408889634f;      // 0.1*log2(e): 2^acc == exp(dot/10)
  u16x4 oc; oc[0] = f2b(c.x * C); oc[1] = f2b(c.y * C);
  oc[2] = f2b(c.z * C); oc[3] = f2b(c.w * C);
  ((u16x4*)ftb)[i] = oc;
  float s = a.x * a.x + a.y * a.y + a.z * a.z + a.w * a.w;
#pragma unroll
  for (int off = 1; off <= 16; off <<= 1) s += __shfl_xor(s, off);
  if ((threadIdx.x & 31) == 0) inv_norm[i >> 5] = 1.0f / sqrtf(s);
}

// ---- kernel 2: ring-3 counted-vmcnt GEMM C[m][n] (r11 body) ----------------
// SINGLE change vs r11: block-index decomposition. r11 put q in the LOW bits,
// so co-resident blocks on a CU (bid, bid+256, ...) had the same q,h but
// DIFFERENT batch b -> five disjoint 64KB B-streams thrash the 32KB L1 and
// every fragment load pays L2 latency. Now b,h are the low bits: co-resident
// blocks share (b,h) -> same B-stream + sInv -> L1/L2-warm tile reads.
__global__ __launch_bounds__(256, 5) void k_main(const unsigned short* __restrict__ fsb,
                                                 const unsigned short* __restrict__ ftb,
                                                 const float* __restrict__ inv_norm,
                                                 float* __restrict__ psum,
                                                 float2* __restrict__ pmax) {
  __shared__ __align__(16) char smem[29696];   // 3x8KB ring + 4KB psb + 1KB sInv
  float* psb  = (float*)(smem + 24576);        // [4 waves][256 n]
  float* sInv = (float*)(smem + 28672);        // [256]

  const int t = threadIdx.x;
  const int w = t >> 6, lane = t & 63;
  const int l15 = lane & 15, g = lane >> 4;
  const int bid = blockIdx.x;
  const int b = bid & 3, h = (bid >> 2) & 15, q = bid >> 6;   // b,h fast; q slow
  const int m0 = q * 128 + w * 32;

  // staging: 8KB tile = 32 n-rows x 256B K; 2 segs/thread, involution swizzle
  const int r0 = t >> 4, cp0 = t & 15;
  const int src0 = r0 * 256 + ((cp0 ^ (r0 & 15)) << 4);               // rows 0..15
  const int src1 = (16 + r0) * 256 + ((cp0 ^ ((16 + r0) & 15)) << 4); // rows 16..31
  const int lds0 = w * 1024, lds1 = 4096 + w * 1024;   // wave-uniform bases

  // A fragments: ft rows m0..m0+31 (pre-scaled), straight from global, once
  const unsigned short* Ab = ftb + ((size_t)b * NN + m0) * DD;
  bf16x8 af[4][2];
#pragma unroll
  for (int kk = 0; kk < 4; kk++)
#pragma unroll
    for (int mf = 0; mf < 2; mf++)
      af[kk][mf] = *(const bf16x8*)(Ab + (mf * 16 + l15) * DD + kk * 32 + g * 8);

  // inv_norm slice -> LDS table (read in-loop via ds_read: lgkm domain only)
  sInv[t] = inv_norm[(size_t)b * NN + h * 256 + t];

  const char* gB0 = (const char*)(fsb + ((size_t)b * NN + h * 256) * DD);

  // drain ALL vmem (af loads) + publish sInv BEFORE any prefetch is in flight
  __syncthreads();

  char* b0 = smem;            // compute buffer (tile it)
  char* b1 = smem + 8192;     // tile it+1
  char* b2 = smem + 16384;    // tile it+2 (staging target)

  // prologue: stage tiles 0 and 1 -> 4 loads outstanding
  gload16(gB0 + src0, b0 + lds0);
  gload16(gB0 + src1, b0 + lds1);
  gload16(gB0 + 8192 + src0, b1 + lds0);
  gload16(gB0 + 8192 + src1, b1 + lds1);

  float bkey[2][4];
#pragma unroll
  for (int mf = 0; mf < 2; mf++)
#pragma unroll
    for (int j = 0; j < 4; j++) bkey[mf][j] = 0.0f;

#pragma unroll 1
  for (int it = 0; it < NIT - 1; ++it) {
    // tile it's 2 loads retired; tile it+1's 2 stay in flight
    asm volatile("s_waitcnt vmcnt(2)" ::: "memory");
    __builtin_amdgcn_s_barrier();   // all waves: tile it ready, ring slot free
    if (it < NIT - 2) {             // stage tile it+2 into b2
      const char* gBn = gB0 + (it + 2) * 8192;
      gload16(gBn + src0, b2 + lds0);
      gload16(gBn + src1, b2 + lds1);
    }
    // per-tile n-scales from LDS
    float svn[2];
    svn[0] = sInv[it * 32 + l15];
    svn[1] = sInv[it * 32 + 16 + l15];

    // MFMA: 32 m x 32 n, K=128
    f32x4 acc[2][2] = {};
#pragma unroll
    for (int kk = 0; kk < 4; kk++) {
      bf16x8 bf[2];
#pragma unroll
      for (int fj = 0; fj < 2; fj++)
        bf[fj] = *(const bf16x8*)(b0 + (fj * 16 + l15) * 256 + (((kk * 4 + g) ^ l15) << 4));
#pragma unroll
      for (int mf = 0; mf < 2; mf++)
#pragma unroll
        for (int fj = 0; fj < 2; fj++)
          mfma_16x16x32_bf16(acc[mf][fj], af[kk][mf], bf[fj]);
    }
    // exp col-sums over this wave's 32 m (acc = dot*0.1*log2e -> 2^acc)
#pragma unroll
    for (int fj = 0; fj < 2; fj++) {
      float e0 = vexp2(acc[0][fj][0]), e1 = vexp2(acc[0][fj][1]);
      float e2 = vexp2(acc[0][fj][2]), e3 = vexp2(acc[0][fj][3]);
      float e4 = vexp2(acc[1][fj][0]), e5 = vexp2(acc[1][fj][1]);
      float e6 = vexp2(acc[1][fj][2]), e7 = vexp2(acc[1][fj][3]);
      float s = ((e0 + e1) + (e2 + e3)) + ((e4 + e5) + (e6 + e7));
      s += __shfl_xor(s, 16);
      s += __shfl_xor(s, 32);
      if (g == 0) psb[w * 256 + it * 32 + fj * 16 + l15] = s;
    }
    // packed-key running argmax over n (fma, and_or, max per elem)
    const unsigned codebase = (unsigned)((7 - it) << 1);
#pragma unroll
    for (int fj = 0; fj < 2; fj++) {
      const unsigned code = codebase | (unsigned)(1 - fj);   // bigger = earlier n
#pragma unroll
      for (int mf = 0; mf < 2; mf++)
#pragma unroll
        for (int j = 0; j < 4; j++) {
          float v = fmaf(acc[mf][fj][j], svn[fj], 4.0f);     // positive -> uint order
          unsigned kb = (__float_as_uint(v) & 0xFFFFFFF0u) | code;
          bkey[mf][j] = fmaxf(bkey[mf][j], __uint_as_float(kb));
        }
    }
    char* tmp = b0; b0 = b1; b1 = b2; b2 = tmp;   // rotate ring
  }

  // epilogue iteration (it = NIT-1): only its own 2 loads outstanding
  {
    const int it = NIT - 1;
    asm volatile("s_waitcnt vmcnt(0)" ::: "memory");
    __builtin_amdgcn_s_barrier();
    float svn[2];
    svn[0] = sInv[it * 32 + l15];
    svn[1] = sInv[it * 32 + 16 + l15];
    f32x4 acc[2][2] = {};
#pragma unroll
    for (int kk = 0; kk < 4; kk++) {
      bf16x8 bf[2];
#pragma unroll
      for (int fj = 0; fj < 2; fj++)
        bf[fj] = *(const bf16x8*)(b0 + (fj * 16 + l15) * 256 + (((kk * 4 + g) ^ l15) << 4));
#pragma unroll
      for (int mf = 0; mf < 2; mf++)
#pragma unroll
        for (int fj = 0; fj < 2; fj++)
          mfma_16x16x32_bf16(acc[mf][fj], af[kk][mf], bf[fj]);
    }
#pragma unroll
    for (int fj = 0; fj < 2; fj++) {
      float e0 = vexp2(acc[0][fj][0]), e1 = vexp2(acc[0][fj][1]);
      float e2 = vexp2(acc[0][fj][2]), e3 = vexp2(acc[0][fj][3]);
      float e4 = vexp2(acc[1][fj][0]), e5 = vexp2(acc[1][fj][1]);
      float e6 = vexp2(acc[1][fj][2]), e7 = vexp2(acc[1][fj][3]);
      float s = ((e0 + e1) + (e2 + e3)) + ((e4 + e5) + (e6 + e7));
      s += __shfl_xor(s, 16);
      s += __shfl_xor(s, 32);
      if (g == 0) psb[w * 256 + it * 32 + fj * 16 + l15] = s;
    }
    const unsigned codebase = 0u;
#pragma unroll
    for (int fj = 0; fj < 2; fj++) {
      const unsigned code = codebase | (unsigned)(1 - fj);
#pragma unroll
      for (int mf = 0; mf < 2; mf++)
#pragma unroll
        for (int j = 0; j < 4; j++) {
          float v = fmaf(acc[mf][fj][j], svn[fj], 4.0f);
          unsigned kb = (__float_as_uint(v) & 0xFFFFFFF0u) | code;
          bkey[mf][j] = fmaxf(bkey[mf][j], __uint_as_float(kb));
        }
    }
  }
  __syncthreads();   // psb complete block-wide (full drain: loop is done)

  // psum write-out: combine 4 waves, coalesced (layout psum[b][q][n])
  {
    float s4 = (psb[t] + psb[256 + t]) + (psb[512 + t] + psb[768 + t]);
    psum[((size_t)(b * QG + q)) * NN + h * 256 + t] = s4;
  }

  // pmax finalize: exact cross-l15 argmax, once
#pragma unroll
  for (int mf = 0; mf < 2; mf++)
#pragma unroll
    for (int j = 0; j < 4; j++) {
      unsigned bits = __float_as_uint(bkey[mf][j]);
      unsigned code = bits & 15u;
      int itw = 7 - (int)(code >> 1);
      int fjw = 1 - (int)(code & 1u);
      int n = h * 256 + itw * 32 + fjw * 16 + l15;
      float vq = __uint_as_float(bits & 0xFFFFFFF0u);
#pragma unroll
      for (int off = 1; off <= 8; off <<= 1) {
        float ov = __shfl_xor(vq, off);
        int   on = __shfl_xor(n, off);
        if (ov > vq || (ov == vq && on < n)) { vq = ov; n = on; }
      }
      if (l15 == 0) {
        int m = m0 + mf * 16 + g * 4 + j;
        float2 pr; pr.x = vq; pr.y = __int_as_float(n);
        pmax[((size_t)b * NN + m) * HS + h] = pr;
      }
    }
}

// ---- kernel 3: per-row finish: argmax over 16 slices, sum 32 psum, pos dot -
__global__ __launch_bounds__(256) void k_post(const float* __restrict__ fs,
                                              const float* __restrict__ ft,
                                              const float* __restrict__ psum,
                                              const float2* __restrict__ pmax,
                                              float* __restrict__ blockpart) {
  __shared__ float part[4];
  int w = threadIdx.x >> 6, lane = threadIdx.x & 63;
  int row = blockIdx.x * 4 + w;          // flat b*N + p
  int b = row >> 12, pn = row & (NN - 1);
  // argmax over the 16 h-slices
  float v = -INFINITY; int i = 0x7fffffff;
  if (lane < HS) {
    float2 pm = pmax[(size_t)row * HS + lane];
    v = pm.x; i = __float_as_int(pm.y);
  }
#pragma unroll
  for (int off = 1; off <= 8; off <<= 1) {
    float ov = __shfl_xor(v, off);
    int   oi = __shfl_xor(i, off);
    if (ov > v || (ov == v && oi < i)) { v = ov; i = oi; }
  }
  int j = __shfl(i, 0);
  // sum the 32 q-partials of all_exp
  float tot = (lane < QG) ? psum[((size_t)(b * QG + lane)) * NN + pn] : 0.0f;
#pragma unroll
  for (int off = 1; off <= 16; off <<= 1) tot += __shfl_xor(tot, off);
  // fp32 dot of fs[row] with ft[b, j]
  float2 a = ((const float2*)(fs + (size_t)row * DD))[lane];
  float2 c = ((const float2*)(ft + ((size_t)b * NN + j) * DD))[lane];
  float s = a.x * c.x + a.y * c.y;
#pragma unroll
  for (int off = 32; off > 0; off >>= 1) s += __shfl_xor(s, off);
  if (lane == 0) {
    float term = logf(tot) - s * 0.1f;
    part[w] = fminf(term, 92.103403719761827f);   // ratio clip at 1e-40
  }
  __syncthreads();
  if (threadIdx.x == 0)
    blockpart[blockIdx.x] = part[0] + part[1] + part[2] + part[3];
}

// ---- kernel 4: final deterministic reduction ------------------------------
__global__ __launch_bounds__(256) void k_final(const float* __restrict__ blockpart,
                                               float* __restrict__ out) {
  __shared__ float red[256];
  float s = 0.0f;
  for (int i = threadIdx.x; i < (BB * NN) / 4; i += 256) s += blockpart[i];
  red[threadIdx.x] = s;
  __syncthreads();
  for (int st = 128; st > 0; st >>= 1) {
    if (threadIdx.x < st) red[threadIdx.x] += red[threadIdx.x + st];
    __syncthreads();
  }
  if (threadIdx.x == 0) out[0] = red[0] * (1.0f / (BB * NN));
}

extern "C" void kernel_launch(void* const* d_in, const int* in_sizes, int n_in,
                              void* d_out, int out_size, void* d_ws, size_t ws_size,
                              hipStream_t stream) {
  const float* fs = (const float*)d_in[0];
  const float* ft = (const float*)d_in[1];
  float* out = (float*)d_out;

  const size_t NE = (size_t)BB * NN * DD;
  unsigned short* fsb = (unsigned short*)d_ws;                   // 4MB
  unsigned short* ftb = fsb + NE;                                // 4MB
  float*  inv_norm = (float*)(ftb + NE);                         // 64KB
  float*  psum     = inv_norm + (size_t)BB * NN;                 // B*32*N f32 (2MB)
  float2* pmax     = (float2*)(psum + (size_t)BB * QG * NN);     // B*N*16 f32x2 (2MB)
  float*  blockpart = (float*)(pmax + (size_t)BB * NN * HS);     // B*N/4 f32

  k_prep<<<(int)(NE / 4 / 256), 256, 0, stream>>>(fs, ft, fsb, ftb, inv_norm);
  // k_main: 2048 blocks; decomposition b,h fast / q slow (L1 stream sharing)
  k_main<<<BB * HS * QG, 256, 0, stream>>>(fsb, ftb, inv_norm, psum, pmax);
  k_post<<<(BB * NN) / 4, 256, 0, stream>>>(fs, ft, psum, pmax, blockpart);
  k_final<<<1, 256, 0, stream>>>(blockpart, out);
}